// Round 6
// baseline (269.720 us; speedup 1.0000x reference)
//
#include <hip/hip_runtime.h>

#define BATCH 16384
#define SEQ 512

typedef float f4 __attribute__((ext_vector_type(4)));
typedef _Float16 half4 __attribute__((ext_vector_type(4)));
typedef _Float16 half8 __attribute__((ext_vector_type(8)));

// Activation inputs pre-scaled into the weights:
//   sigmoid rows (i,f,o): x -log2(e)  -> A=exp2(p), sig = 1/(1+A)
//   tanh row (g):         x -2log2(e) -> B=exp2(p), tanh=(1-B)/(1+B)
#define SIGS (-1.44269504088896f)
#define TNHS (-2.88539008177793f)
#define NTNH (2.88539008177793f)

union HB2 { unsigned int u[2]; half4 h; };
union HB4 { unsigned int u[4]; half8 h; };

__device__ __forceinline__ float bpermf(int addr, float v) {
    return __int_as_float(__builtin_amdgcn_ds_bpermute(addr, __float_as_int(v)));
}
__device__ __forceinline__ unsigned int h16(float v) {  // fp16 bits (RNE), low half
    return (unsigned int)__builtin_bit_cast(unsigned short, (_Float16)v);
}
// packed f32->f16x2 (RTZ), one instruction
__device__ __forceinline__ unsigned int pk2(float a, float b) {
    return __builtin_bit_cast(unsigned int, __builtin_amdgcn_cvt_pkrtz(a, b));
}
// v_perm_b32 halfword packer: a.lo | b.lo<<16
__device__ __forceinline__ unsigned int lolo(unsigned int a, unsigned int b) {
    return __builtin_amdgcn_perm(b, a, 0x05040100u);
}

// ws layout (per-g contiguous float2 pairs): ws[g*1024 + 2t] = Wc[t*5+g],
// ws[g*1024 + 2t + 1] = Wc[t*5+4]. Wc = W2@W1 (MLP collapses). ws[4096]=cbias.
__global__ __launch_bounds__(256) void collapse_kernel(
    const float* __restrict__ W1, const float* __restrict__ b1,
    const float* __restrict__ W2, const float* __restrict__ b2,
    float* __restrict__ ws)
{
    const int kl = threadIdx.x & 15;
    const int ms = threadIdx.x >> 4;          // 0..15, 32 rows each
    const int k  = blockIdx.x * 16 + kl;      // 160 blocks * 16 = 2560
    const float* w1p = W1 + (size_t)(ms * 32) * 2560 + k;
    const float* w2p = W2 + ms * 32;
    float acc = 0.f;
    #pragma unroll 8
    for (int m = 0; m < 32; ++m) acc = fmaf(w2p[m], w1p[(size_t)m * 2560], acc);
    __shared__ float red[16][17];
    red[ms][kl] = acc;
    __syncthreads();
    if (ms == 0) {
        float s = 0.f;
        #pragma unroll
        for (int r = 0; r < 16; ++r) s += red[r][kl];
        const int t = k / 5, u = k % 5;
        if (u < 4) ws[(u << 10) + 2 * t] = s;
        else {
            ws[2*t + 1] = s;        ws[1024 + 2*t + 1] = s;
            ws[2048 + 2*t + 1] = s; ws[3072 + 2*t + 1] = s;
        }
    }
    if (blockIdx.x == 0) {
        const int t = threadIdx.x;
        float p = fmaf(W2[t], b1[t], W2[t + 256] * b1[t + 256]);
        #pragma unroll
        for (int off = 32; off > 0; off >>= 1) p += __shfl_down(p, off);
        __shared__ float cred[4];
        if ((t & 63) == 0) cred[t >> 6] = p;
        __syncthreads();
        if (t == 0) ws[4096] = cred[0] + cred[1] + cred[2] + cred[3] + b2[0];
    }
}

// Bperm-free MFMA LSTM, 3-MFMA body, TWO independent 16-element streams per
// wave (P: e, Q: e+8192). Streams share weight fragments, biases, selectors
// and the ws prefetch; their dependency graphs are independent, so stream Q's
// issue fills stream P's trans-latency spine and vice versa (software SMT for
// a 1-wave/SIMD latency-bound kernel). 512 blocks.
// Per-stream body:
//   dA  = 16x16x16(aL0a, B0)              -- L0 cells 0..3
//   dU  = 16x16x32(aU,  {B0,0,B1lo,B1hi}) -- L0u4 + L1u4 in one mfma
//   dC  = 16x16x16(aL1a, B1)              -- L1 cells 0..3, slack 1 step
// K-slot layout (every B half-word produced by the lane that packs it):
//   B0: g0:{h0u0, x}  g1:{h0u1, h0u4}  g2:{h0u2}  g3:{h0u3}
//   B1: g:{h0ug, h1ug, (g1:h0u4 / g2:h1u4)}
// Unused slots hold garbage x structurally-zero A columns (|h|<=1: no Inf).
__global__ __launch_bounds__(64)
__attribute__((amdgpu_waves_per_eu(1, 1)))
void lstm_fused_kernel(
    const float* __restrict__ x,
    const float* __restrict__ Wih0, const float* __restrict__ Whh0,
    const float* __restrict__ bih0, const float* __restrict__ bhh0,
    const float* __restrict__ Wih1, const float* __restrict__ Whh1,
    const float* __restrict__ bih1, const float* __restrict__ bhh1,
    const float* __restrict__ ws, float* __restrict__ out)
{
    const int lane = threadIdx.x;
    const int e15  = lane & 15;
    const int g    = lane >> 4;          // k-block / lane group / cell index
    const int e    = blockIdx.x * 16 + e15;     // stream P element; Q = e + 8192
    const float sc[4] = {SIGS, SIGS, TNHS, SIGS};

    // ---- A fragments (weights, fp16), shared by both streams ----
    HB2 aL0a, aL1a;
    HB4 aU;
    {
        const int m = e15;
        {   // L0a: row m -> cell u=m>>2, gate gi=m&3; k0=Whh0[.][g], k1: g0->x, g1->h0u4
            const int u = m >> 2, gi = m & 3, gr = gi * 5 + u;
            const float s = sc[gi];
            float w0 = Whh0[gr * 5 + g];
            float w1 = (g == 0) ? Wih0[gr] : (g == 1 ? Whh0[gr * 5 + 4] : 0.f);
            aL0a.u[0] = h16(w0 * s) | (h16(w1 * s) << 16);
            aL0a.u[1] = 0u;
        }
        {   // L1a: slot0=Wih1[.][g], slot1=Whh1[.][g], slot2: g1->Wih1[.][4], g2->Whh1[.][4]
            const int u = m >> 2, gi = m & 3, gr = gi * 5 + u;
            const float s = sc[gi];
            float w0 = Wih1[gr * 5 + g];
            float w1 = Whh1[gr * 5 + g];
            float w2 = (g == 1) ? Wih1[gr * 5 + 4] : (g == 2 ? Whh1[gr * 5 + 4] : 0.f);
            aL1a.u[0] = h16(w0 * s) | (h16(w1 * s) << 16);
            aL1a.u[1] = h16(w2 * s);
        }
        {   // aU j0-1: L0b (rows 4..7 = L0u4 gates, B0 column map)
            float w0 = 0.f, w1 = 0.f, s = 0.f;
            if (m >= 4 && m < 8) {
                const int gi = m - 4, gr = gi * 5 + 4;
                s = sc[gi];
                w0 = Whh0[gr * 5 + g];
                w1 = (g == 0) ? Wih0[gr] : (g == 1 ? Whh0[gr * 5 + 4] : 0.f);
            }
            aU.u[0] = h16(w0 * s) | (h16(w1 * s) << 16);
            aU.u[1] = 0u;
        }
        {   // aU j4-6: L1b (rows 8..11 = L1u4 gates, B1 column map)
            float w0 = 0.f, w1 = 0.f, w2 = 0.f, s = 0.f;
            if (m >= 8 && m < 12) {
                const int gi = m - 8, gr = gi * 5 + 4;
                s = sc[gi];
                w0 = Wih1[gr * 5 + g];
                w1 = Whh1[gr * 5 + g];
                w2 = (g == 1) ? Wih1[gr * 5 + 4] : (g == 2 ? Whh1[gr * 5 + 4] : 0.f);
            }
            aU.u[2] = h16(w0 * s) | (h16(w1 * s) << 16);
            aU.u[3] = h16(w2 * s);
        }
    }
    // ---- C fragments (biases, fp32): lane reg r -> row 4g+r; cbm merged u4 bias ----
    f4 cL0a, cL1a, cbm;
    #pragma unroll
    for (int r = 0; r < 4; ++r) {
        cL0a[r] = (bih0[r*5+g] + bhh0[r*5+g]) * sc[r];
        cL1a[r] = (bih1[r*5+g] + bhh1[r*5+g]) * sc[r];
        cbm[r]  = (g == 1) ? (bih0[r*5+4] + bhh0[r*5+4]) * sc[r]
                : (g == 2) ? (bih1[r*5+4] + bhh1[r*5+4]) * sc[r] : 0.f;
    }

    const float* xpP = x + (size_t)e * SEQ;
    const float* xpQ = xpP + (size_t)8192 * SEQ;
    const float* wsg = ws + (g << 10);
    const bool isg0 = (g == 0), isg2 = (g == 2);
    // per-lane perm selectors for B0: low16 = hx0.lo; high16 = g0 ? xpair.(lo/hi) : hx0.hi
    const unsigned selA = isg0 ? 0x05040100u : 0x03020100u;
    const unsigned selB = isg0 ? 0x07060100u : 0x03020100u;

    // ---- per-stream state ----
    float cs0P = 0.f, cs1P = 0.f, cs4P = 0.f, accP = 0.f, acc4P = 0.f;
    float cs0Q = 0.f, cs1Q = 0.f, cs4Q = 0.f, accQ = 0.f, acc4Q = 0.f;
    f4 dAP, dCP, dUP, dAQ, dCQ, dUQ;

    // ---- prologue: step 0 (L0 real; L1 state forced to zero) ----
    auto prologue = [&](const float* xp, f4& dA, f4& dU, f4& dC,
                        float& cs0, float& cs4) {
        float2 x01 = *(const float2*)xp;
        unsigned xh0 = h16(x01.x), xh1 = h16(x01.y);
        HB2 b0; b0.u[0] = isg0 ? (xh0 << 16) : 0u; b0.u[1] = 0u;  // k1 = x(0)
        dA = __builtin_amdgcn_mfma_f32_16x16x16f16(aL0a.h, b0.h, cL0a, 0, 0, 0);
        HB4 bu0; bu0.u[0] = b0.u[0]; bu0.u[1] = bu0.u[2] = bu0.u[3] = 0u;
        dU = __builtin_amdgcn_mfma_f32_16x16x32_f16(aU.h, bu0.h, cbm, 0, 0, 0);
        float A0 = __builtin_amdgcn_exp2f(dA[0]), F0 = __builtin_amdgcn_exp2f(dA[1]);
        float B0 = __builtin_amdgcn_exp2f(dA[2]), O0 = __builtin_amdgcn_exp2f(dA[3]);
        float A1 = __builtin_amdgcn_exp2f(dU[0]), F1 = __builtin_amdgcn_exp2f(dU[1]);
        float B1 = __builtin_amdgcn_exp2f(dU[2]), O1 = __builtin_amdgcn_exp2f(dU[3]);
        float t0 = 1.f + A0, t1 = 1.f + A1;
        float ab0 = fmaf(t0, B0, t0), ab1 = fmaf(t1, B1, t1);
        float D0 = fmaf(ab0, F0, ab0), D1 = fmaf(ab1, F1, ab1);
        float r0 = __builtin_amdgcn_rcpf(D0), r1 = __builtin_amdgcn_rcpf(D1);
        float bs0 = fmaf(B0, NTNH, TNHS), bs1 = fmaf(B1, NTNH, TNHS);
        float w0 = fmaf(bs0, F0, bs0), w1 = fmaf(bs1, F1, bs1);
        cs0 = fmaf(ab0, cs0, w0) * r0;
        cs4 = fmaf(ab1, cs4, w1) * r1;
        float Ce0 = __builtin_amdgcn_exp2f(fminf(cs0, 17.f));
        float Ce1 = __builtin_amdgcn_exp2f(fminf(cs4, 17.f));
        float o0 = 1.f + O0, o1 = 1.f + O1;
        float e0 = fmaf(o0, Ce0, o0), e1 = fmaf(o1, Ce1, o1);
        float hA = (1.f - Ce0) * __builtin_amdgcn_rcpf(e0);
        float h4 = (1.f - Ce1) * __builtin_amdgcn_rcpf(e1);
        if (isg2) { h4 = 0.f; cs4 = 0.f; }   // h1u4(-1) = 0
        unsigned hx0 = pk2(hA, h4);
        HB2 B0n, B1n;
        B0n.u[0] = isg0 ? lolo(hx0, xh1) : hx0;  B0n.u[1] = 0u;
        dA = __builtin_amdgcn_mfma_f32_16x16x16f16(aL0a.h, B0n.h, cL0a, 0, 0, 0);
        B1n.u[0] = pk2(hA, 0.f);  B1n.u[1] = hx0 >> 16;   // hC(-1) = 0
        HB4 BU; BU.u[0] = B0n.u[0]; BU.u[1] = 0u; BU.u[2] = B1n.u[0]; BU.u[3] = B1n.u[1];
        dU = __builtin_amdgcn_mfma_f32_16x16x32_f16(aU.h, BU.h, cbm, 0, 0, 0);
        dC = __builtin_amdgcn_mfma_f32_16x16x16f16(aL1a.h, B1n.h, cL1a, 0, 0, 0);
    };
    prologue(xpP, dAP, dUP, dCP, cs0P, cs4P);
    prologue(xpQ, dAQ, dUQ, dCQ, cs0Q, cs4Q);

    // body(step m, one stream): exps, {01-shared, 2-private} rcps, chain2 first,
    // spine chains 0&1, packs, MFMAs in order dA -> dU(spine) -> dC(slack)
    auto body = [&](f4& dA, f4& dU, f4& dC, float& cs0, float& cs4, float& cs1,
                    float& acc, float& acc4,
                    unsigned xpair, unsigned sel, float wMu, float w4u) {
        float A0 = __builtin_amdgcn_exp2f(dA[0]), F0 = __builtin_amdgcn_exp2f(dA[1]);
        float B0 = __builtin_amdgcn_exp2f(dA[2]), O0 = __builtin_amdgcn_exp2f(dA[3]);
        float A1 = __builtin_amdgcn_exp2f(dU[0]), F1 = __builtin_amdgcn_exp2f(dU[1]);
        float B1 = __builtin_amdgcn_exp2f(dU[2]), O1 = __builtin_amdgcn_exp2f(dU[3]);
        float A2 = __builtin_amdgcn_exp2f(dC[0]), F2 = __builtin_amdgcn_exp2f(dC[1]);
        float B2 = __builtin_amdgcn_exp2f(dC[2]), O2 = __builtin_amdgcn_exp2f(dC[3]);
        float t0 = 1.f + A0, t1 = 1.f + A1, t2 = 1.f + A2;
        float ab0 = fmaf(t0, B0, t0), ab1 = fmaf(t1, B1, t1), ab2 = fmaf(t2, B2, t2);
        float D0 = fmaf(ab0, F0, ab0), D1 = fmaf(ab1, F1, ab1), D2 = fmaf(ab2, F2, ab2);
        float r01 = __builtin_amdgcn_rcpf(D0 * D1);   // spine pair, no D2 coupling
        float r0 = r01 * D1, r1 = r01 * D0;
        float r2 = __builtin_amdgcn_rcpf(D2);         // slack chain private
        float bs0 = fmaf(B0, NTNH, TNHS), bs1 = fmaf(B1, NTNH, TNHS), bs2 = fmaf(B2, NTNH, TNHS);
        float w0 = fmaf(bs0, F0, bs0), w1 = fmaf(bs1, F1, bs1), w2 = fmaf(bs2, F2, bs2);
        cs0 = fmaf(ab0, cs0, w0) * r0;      // TNHS-scaled c; post-rcp = 1 mul
        cs4 = fmaf(ab1, cs4, w1) * r1;
        cs1 = fmaf(ab2, cs1, w2) * r2;
        // chain 2 output FIRST (h1u_g, step m-1): hC ready before spine tail
        float Ce2 = __builtin_amdgcn_exp2f(fminf(cs1, 17.f));
        float o2 = 1.f + O2;
        float e2 = fmaf(o2, Ce2, o2);
        float hC = (1.f - Ce2) * __builtin_amdgcn_rcpf(e2);
        acc  = fmaf(hC, wMu, acc);              // fused MLP head (t = m-1)
        // chains 0&1 output (spine): shared rcp
        float Ce0 = __builtin_amdgcn_exp2f(fminf(cs0, 17.f));
        float Ce1 = __builtin_amdgcn_exp2f(fminf(cs4, 17.f));
        float o0 = 1.f + O0, o1 = 1.f + O1;
        float e0 = fmaf(o0, Ce0, o0), e1 = fmaf(o1, Ce1, o1);
        float rr = __builtin_amdgcn_rcpf(e0 * e1);
        float hA = (1.f - Ce0) * (rr * e1);     // h0u_g (step m)
        float h4 = (1.f - Ce1) * (rr * e0);     // g1: h0u4, g2: h1u4
        acc4 = fmaf(h4, w4u, acc4);             // only g2's (h1u4) is used
        unsigned hx0  = pk2(hA, h4);
        unsigned b1lo = pk2(hA, hC);
        unsigned b1hi = hx0 >> 16;
        HB2 B0n;
        B0n.u[0] = __builtin_amdgcn_perm(xpair, hx0, sel);  B0n.u[1] = 0u;
        dA = __builtin_amdgcn_mfma_f32_16x16x16f16(aL0a.h, B0n.h, cL0a, 0, 0, 0);
        HB4 BU; BU.u[0] = B0n.u[0]; BU.u[1] = 0u; BU.u[2] = b1lo; BU.u[3] = b1hi;
        dU = __builtin_amdgcn_mfma_f32_16x16x32_f16(aU.h, BU.h, cbm, 0, 0, 0);  // spine
        HB2 B1n; B1n.u[0] = b1lo; B1n.u[1] = b1hi;
        dC = __builtin_amdgcn_mfma_f32_16x16x16f16(aL1a.h, B1n.h, cL1a, 0, 0, 0);
    };

    #define BODY_P(xq, sl, wm, w4) body(dAP, dUP, dCP, cs0P, cs4P, cs1P, accP, acc4P, xq, sl, wm, w4)
    #define BODY_Q(xq, sl, wm, w4) body(dAQ, dUQ, dCQ, cs0Q, cs4Q, cs1Q, accQ, acc4Q, xq, sl, wm, w4)

    // prefetch buffers for bodies 1..4: x(2..5) packed per stream, Wc shared
    unsigned xqaP, xqbP, xqaQ, xqbQ;  float4 wqa, wqb;
    {
        float2 pa = *(const float2*)(xpP + 2), pb = *(const float2*)(xpP + 4);
        float2 qa = *(const float2*)(xpQ + 2), qb = *(const float2*)(xpQ + 4);
        xqaP = pk2(pa.x, pa.y);  xqbP = pk2(pb.x, pb.y);
        xqaQ = pk2(qa.x, qa.y);  xqbQ = pk2(qb.x, qb.y);
        wqa = *(const float4*)(wsg);
        wqb = *(const float4*)(wsg + 4);
    }
    for (int m = 1; m < 502; m += 4) {          // bodies 1..504, no clamps
        float2 pa = *(const float2*)(xpP + m + 5), pb = *(const float2*)(xpP + m + 7);
        float2 qa = *(const float2*)(xpQ + m + 5), qb = *(const float2*)(xpQ + m + 7);
        unsigned nxaP = pk2(pa.x, pa.y), nxbP = pk2(pb.x, pb.y);
        unsigned nxaQ = pk2(qa.x, qa.y), nxbQ = pk2(qb.x, qb.y);
        float4 nwa = *(const float4*)(wsg + 2 * (m + 3));
        float4 nwb = *(const float4*)(wsg + 2 * (m + 3) + 4);
        BODY_P(xqaP, selA, wqa.x, wqa.y);  BODY_Q(xqaQ, selA, wqa.x, wqa.y);
        BODY_P(xqaP, selB, wqa.z, wqa.w);  BODY_Q(xqaQ, selB, wqa.z, wqa.w);
        BODY_P(xqbP, selA, wqb.x, wqb.y);  BODY_Q(xqbQ, selA, wqb.x, wqb.y);
        BODY_P(xqbP, selB, wqb.z, wqb.w);  BODY_Q(xqbQ, selB, wqb.z, wqb.w);
        xqaP = nxaP; xqbP = nxbP; xqaQ = nxaQ; xqbQ = nxbQ; wqa = nwa; wqb = nwb;
    }
    {   // block m=505 (bodies 505..508): x prefetch clamped, ws t=508..511
        unsigned nxaP = pk2(xpP[510], xpP[511]), nxbP = pk2(xpP[511], xpP[511]);
        unsigned nxaQ = pk2(xpQ[510], xpQ[511]), nxbQ = pk2(xpQ[511], xpQ[511]);
        float4 nwa = *(const float4*)(wsg + 2 * 508);
        float4 nwb = *(const float4*)(wsg + 2 * 508 + 4);
        BODY_P(xqaP, selA, wqa.x, wqa.y);  BODY_Q(xqaQ, selA, wqa.x, wqa.y);
        BODY_P(xqaP, selB, wqa.z, wqa.w);  BODY_Q(xqaQ, selB, wqa.z, wqa.w);
        BODY_P(xqbP, selA, wqb.x, wqb.y);  BODY_Q(xqbQ, selA, wqb.x, wqb.y);
        BODY_P(xqbP, selB, wqb.z, wqb.w);  BODY_Q(xqbQ, selB, wqb.z, wqb.w);
        xqaP = nxaP; xqbP = nxbP; xqaQ = nxaQ; xqbQ = nxbQ; wqa = nwa; wqb = nwb;
    }
    {   // block m=509 (bodies 509..512): no prefetch
        BODY_P(xqaP, selA, wqa.x, wqa.y);  BODY_Q(xqaQ, selA, wqa.x, wqa.y);
        BODY_P(xqaP, selB, wqa.z, wqa.w);  BODY_Q(xqaQ, selB, wqa.z, wqa.w);
        BODY_P(xqbP, selA, wqb.x, wqb.y);  BODY_Q(xqbQ, selA, wqb.x, wqb.y);
        BODY_P(xqbP, selB, wqb.z, wqb.w);  BODY_Q(xqbQ, selB, wqb.z, wqb.w);
    }
    #undef BODY_P
    #undef BODY_Q

    // reduce: element e partials live on lanes e, e+16, e+32(+u4), e+48
    const float cbias = ws[4096];
    {
        float accT = accP + (isg2 ? acc4P : 0.f);
        float t0 = bpermf(e15 << 2, accT);
        float t1 = bpermf((e15 + 16) << 2, accT);
        float t2 = bpermf((e15 + 32) << 2, accT);
        float t3 = bpermf((e15 + 48) << 2, accT);
        if (lane < 16) out[e] = (t0 + t1) + (t2 + t3) + cbias;
    }
    {
        float accT = accQ + (isg2 ? acc4Q : 0.f);
        float t0 = bpermf(e15 << 2, accT);
        float t1 = bpermf((e15 + 16) << 2, accT);
        float t2 = bpermf((e15 + 32) << 2, accT);
        float t3 = bpermf((e15 + 48) << 2, accT);
        if (lane < 16) out[e + 8192] = (t0 + t1) + (t2 + t3) + cbias;
    }
}

extern "C" void kernel_launch(void* const* d_in, const int* in_sizes, int n_in,
                              void* d_out, int out_size, void* d_ws, size_t ws_size,
                              hipStream_t stream) {
    const float* x    = (const float*)d_in[0];
    const float* Wih0 = (const float*)d_in[1];
    const float* Whh0 = (const float*)d_in[2];
    const float* bih0 = (const float*)d_in[3];
    const float* bhh0 = (const float*)d_in[4];
    const float* Wih1 = (const float*)d_in[5];
    const float* Whh1 = (const float*)d_in[6];
    const float* bih1 = (const float*)d_in[7];
    const float* bhh1 = (const float*)d_in[8];
    const float* W1   = (const float*)d_in[9];
    const float* b1   = (const float*)d_in[10];
    const float* W2   = (const float*)d_in[11];
    const float* b2   = (const float*)d_in[12];
    float* out = (float*)d_out;
    float* ws  = (float*)d_ws;

    collapse_kernel<<<160, 256, 0, stream>>>(W1, b1, W2, b2, ws);
    lstm_fused_kernel<<<BATCH / 32, 64, 0, stream>>>(x, Wih0, Whh0, bih0, bhh0,
                                                     Wih1, Whh1, bih1, bhh1, ws, out);
}

// Round 7
// 192.052 us; speedup vs baseline: 1.4044x; 1.4044x over previous
//
#include <hip/hip_runtime.h>

#define BATCH 16384
#define SEQ 512

typedef float f4 __attribute__((ext_vector_type(4)));
typedef _Float16 half4 __attribute__((ext_vector_type(4)));
typedef _Float16 half8 __attribute__((ext_vector_type(8)));

// Activation inputs pre-scaled into the weights:
//   sigmoid rows (i,f,o): x -log2(e)  -> A=exp2(p), sig = 1/(1+A)
//   tanh row (g):         x -2log2(e) -> B=exp2(p), tanh=(1-B)/(1+B)
#define SIGS (-1.44269504088896f)
#define TNHS (-2.88539008177793f)
#define NTNH (2.88539008177793f)

union HB2 { unsigned int u[2]; half4 h; };
union HB4 { unsigned int u[4]; half8 h; };

__device__ __forceinline__ float bpermf(int addr, float v) {
    return __int_as_float(__builtin_amdgcn_ds_bpermute(addr, __float_as_int(v)));
}
__device__ __forceinline__ unsigned int h16(float v) {  // fp16 bits (RNE), low half
    return (unsigned int)__builtin_bit_cast(unsigned short, (_Float16)v);
}
// packed f32->f16x2 (RTZ), one instruction
__device__ __forceinline__ unsigned int pk2(float a, float b) {
    return __builtin_bit_cast(unsigned int, __builtin_amdgcn_cvt_pkrtz(a, b));
}
// v_perm_b32 halfword packer: a.lo | b.lo<<16
__device__ __forceinline__ unsigned int lolo(unsigned int a, unsigned int b) {
    return __builtin_amdgcn_perm(b, a, 0x05040100u);
}

// ws layout (per-g contiguous float2 pairs): ws[g*1024 + 2t] = Wc[t*5+g],
// ws[g*1024 + 2t + 1] = Wc[t*5+4]. Wc = W2@W1 (MLP collapses). ws[4096]=cbias.
__global__ __launch_bounds__(256) void collapse_kernel(
    const float* __restrict__ W1, const float* __restrict__ b1,
    const float* __restrict__ W2, const float* __restrict__ b2,
    float* __restrict__ ws)
{
    const int kl = threadIdx.x & 15;
    const int ms = threadIdx.x >> 4;          // 0..15, 32 rows each
    const int k  = blockIdx.x * 16 + kl;      // 160 blocks * 16 = 2560
    const float* w1p = W1 + (size_t)(ms * 32) * 2560 + k;
    const float* w2p = W2 + ms * 32;
    float acc = 0.f;
    #pragma unroll 8
    for (int m = 0; m < 32; ++m) acc = fmaf(w2p[m], w1p[(size_t)m * 2560], acc);
    __shared__ float red[16][17];
    red[ms][kl] = acc;
    __syncthreads();
    if (ms == 0) {
        float s = 0.f;
        #pragma unroll
        for (int r = 0; r < 16; ++r) s += red[r][kl];
        const int t = k / 5, u = k % 5;
        if (u < 4) ws[(u << 10) + 2 * t] = s;
        else {
            ws[2*t + 1] = s;        ws[1024 + 2*t + 1] = s;
            ws[2048 + 2*t + 1] = s; ws[3072 + 2*t + 1] = s;
        }
    }
    if (blockIdx.x == 0) {
        const int t = threadIdx.x;
        float p = fmaf(W2[t], b1[t], W2[t + 256] * b1[t + 256]);
        #pragma unroll
        for (int off = 32; off > 0; off >>= 1) p += __shfl_down(p, off);
        __shared__ float cred[4];
        if ((t & 63) == 0) cred[t >> 6] = p;
        __syncthreads();
        if (t == 0) ws[4096] = cred[0] + cred[1] + cred[2] + cred[3] + b2[0];
    }
}

// Bperm-free MFMA LSTM, 3-MFMA body (r5 structure), 3-way-merged rcps:
//   dA  = 16x16x16(aL0a, B0)              -- L0 cells 0..3
//   dU  = 16x16x32(aU,  {B0,0,B1lo,B1hi}) -- L0u4 + L1u4 in one mfma
//   dC  = 16x16x16(aL1a, B1)              -- L1 cells 0..3, slack 1 step
// Input side: one grand rcp(D0*D1*D2), per-chain r_i via pair products.
// Output side: one grand rcp(e0*e1*e2). D2/e2 come from the slack chain
// (exps issue early) so the merges add only ~1 mul of spine depth.
// K-slot layout (every B half-word produced by the lane that packs it):
//   B0: g0:{h0u0, x}  g1:{h0u1, h0u4}  g2:{h0u2}  g3:{h0u3}
//   B1: g:{h0ug, h1ug, (g1:h0u4 / g2:h1u4)}
// Unused slots hold garbage x structurally-zero A columns (|h|<=1: no Inf).
__global__ __launch_bounds__(64)
__attribute__((amdgpu_waves_per_eu(1, 1)))
void lstm_fused_kernel(
    const float* __restrict__ x,
    const float* __restrict__ Wih0, const float* __restrict__ Whh0,
    const float* __restrict__ bih0, const float* __restrict__ bhh0,
    const float* __restrict__ Wih1, const float* __restrict__ Whh1,
    const float* __restrict__ bih1, const float* __restrict__ bhh1,
    const float* __restrict__ ws, float* __restrict__ out)
{
    const int lane = threadIdx.x;
    const int e15  = lane & 15;
    const int g    = lane >> 4;          // k-block / lane group / cell index
    const int e    = blockIdx.x * 16 + e15;
    const float sc[4] = {SIGS, SIGS, TNHS, SIGS};

    // ---- A fragments (weights, fp16) ----
    HB2 aL0a, aL1a;
    HB4 aU;
    {
        const int m = e15;
        {   // L0a: row m -> cell u=m>>2, gate gi=m&3; k0=Whh0[.][g], k1: g0->x, g1->h0u4
            const int u = m >> 2, gi = m & 3, gr = gi * 5 + u;
            const float s = sc[gi];
            float w0 = Whh0[gr * 5 + g];
            float w1 = (g == 0) ? Wih0[gr] : (g == 1 ? Whh0[gr * 5 + 4] : 0.f);
            aL0a.u[0] = h16(w0 * s) | (h16(w1 * s) << 16);
            aL0a.u[1] = 0u;
        }
        {   // L1a: slot0=Wih1[.][g], slot1=Whh1[.][g], slot2: g1->Wih1[.][4], g2->Whh1[.][4]
            const int u = m >> 2, gi = m & 3, gr = gi * 5 + u;
            const float s = sc[gi];
            float w0 = Wih1[gr * 5 + g];
            float w1 = Whh1[gr * 5 + g];
            float w2 = (g == 1) ? Wih1[gr * 5 + 4] : (g == 2 ? Whh1[gr * 5 + 4] : 0.f);
            aL1a.u[0] = h16(w0 * s) | (h16(w1 * s) << 16);
            aL1a.u[1] = h16(w2 * s);
        }
        {   // aU j0-1: L0b (rows 4..7 = L0u4 gates, B0 column map)
            float w0 = 0.f, w1 = 0.f, s = 0.f;
            if (m >= 4 && m < 8) {
                const int gi = m - 4, gr = gi * 5 + 4;
                s = sc[gi];
                w0 = Whh0[gr * 5 + g];
                w1 = (g == 0) ? Wih0[gr] : (g == 1 ? Whh0[gr * 5 + 4] : 0.f);
            }
            aU.u[0] = h16(w0 * s) | (h16(w1 * s) << 16);
            aU.u[1] = 0u;
        }
        {   // aU j4-6: L1b (rows 8..11 = L1u4 gates, B1 column map)
            float w0 = 0.f, w1 = 0.f, w2 = 0.f, s = 0.f;
            if (m >= 8 && m < 12) {
                const int gi = m - 8, gr = gi * 5 + 4;
                s = sc[gi];
                w0 = Wih1[gr * 5 + g];
                w1 = Whh1[gr * 5 + g];
                w2 = (g == 1) ? Wih1[gr * 5 + 4] : (g == 2 ? Whh1[gr * 5 + 4] : 0.f);
            }
            aU.u[2] = h16(w0 * s) | (h16(w1 * s) << 16);
            aU.u[3] = h16(w2 * s);
        }
    }
    // ---- C fragments (biases, fp32): lane reg r -> row 4g+r; cbm merged u4 bias ----
    f4 cL0a, cL1a, cbm;
    #pragma unroll
    for (int r = 0; r < 4; ++r) {
        cL0a[r] = (bih0[r*5+g] + bhh0[r*5+g]) * sc[r];
        cL1a[r] = (bih1[r*5+g] + bhh1[r*5+g]) * sc[r];
        cbm[r]  = (g == 1) ? (bih0[r*5+4] + bhh0[r*5+4]) * sc[r]
                : (g == 2) ? (bih1[r*5+4] + bhh1[r*5+4]) * sc[r] : 0.f;
    }

    const float* xp  = x + (size_t)e * SEQ;
    const float* wsg = ws + (g << 10);
    const bool isg0 = (g == 0), isg2 = (g == 2);
    // per-lane perm selectors for B0: low16 = hx0.lo; high16 = g0 ? xpair.(lo/hi) : hx0.hi
    const unsigned selA = isg0 ? 0x05040100u : 0x03020100u;
    const unsigned selB = isg0 ? 0x07060100u : 0x03020100u;

    float cs0 = 0.f, cs1 = 0.f, cs4 = 0.f, acc = 0.f, acc4 = 0.f;
    f4 dA, dC, dU;

    // ---- prologue: step 0 (L0 real; L1 state forced to zero) ----
    {
        float2 x01 = *(const float2*)xp;
        unsigned xh0 = h16(x01.x), xh1 = h16(x01.y);
        HB2 b0; b0.u[0] = isg0 ? (xh0 << 16) : 0u; b0.u[1] = 0u;  // k1 = x(0)
        dA = __builtin_amdgcn_mfma_f32_16x16x16f16(aL0a.h, b0.h, cL0a, 0, 0, 0);
        HB4 bu0; bu0.u[0] = b0.u[0]; bu0.u[1] = bu0.u[2] = bu0.u[3] = 0u;
        dU = __builtin_amdgcn_mfma_f32_16x16x32_f16(aU.h, bu0.h, cbm, 0, 0, 0);
        // 2-chain act (private rcps), TNHS-scaled cell state
        float A0 = __builtin_amdgcn_exp2f(dA[0]), F0 = __builtin_amdgcn_exp2f(dA[1]);
        float B0 = __builtin_amdgcn_exp2f(dA[2]), O0 = __builtin_amdgcn_exp2f(dA[3]);
        float A1 = __builtin_amdgcn_exp2f(dU[0]), F1 = __builtin_amdgcn_exp2f(dU[1]);
        float B1 = __builtin_amdgcn_exp2f(dU[2]), O1 = __builtin_amdgcn_exp2f(dU[3]);
        float t0 = 1.f + A0, t1 = 1.f + A1;
        float ab0 = fmaf(t0, B0, t0), ab1 = fmaf(t1, B1, t1);
        float D0 = fmaf(ab0, F0, ab0), D1 = fmaf(ab1, F1, ab1);
        float r0 = __builtin_amdgcn_rcpf(D0), r1 = __builtin_amdgcn_rcpf(D1);
        float bs0 = fmaf(B0, NTNH, TNHS), bs1 = fmaf(B1, NTNH, TNHS);
        float w0 = fmaf(bs0, F0, bs0), w1 = fmaf(bs1, F1, bs1);
        cs0 = fmaf(ab0, cs0, w0) * r0;
        cs4 = fmaf(ab1, cs4, w1) * r1;
        float Ce0 = __builtin_amdgcn_exp2f(fminf(cs0, 17.f));
        float Ce1 = __builtin_amdgcn_exp2f(fminf(cs4, 17.f));
        float o0 = 1.f + O0, o1 = 1.f + O1;
        float e0 = fmaf(o0, Ce0, o0), e1 = fmaf(o1, Ce1, o1);
        float hA = (1.f - Ce0) * __builtin_amdgcn_rcpf(e0);
        float h4 = (1.f - Ce1) * __builtin_amdgcn_rcpf(e1);
        if (isg2) { h4 = 0.f; cs4 = 0.f; }   // h1u4(-1) = 0
        unsigned hx0 = pk2(hA, h4);
        HB2 B0n, B1n;
        B0n.u[0] = isg0 ? lolo(hx0, xh1) : hx0;  B0n.u[1] = 0u;
        dA = __builtin_amdgcn_mfma_f32_16x16x16f16(aL0a.h, B0n.h, cL0a, 0, 0, 0);
        B1n.u[0] = pk2(hA, 0.f);  B1n.u[1] = hx0 >> 16;   // hC(-1) = 0
        HB4 BU; BU.u[0] = B0n.u[0]; BU.u[1] = 0u; BU.u[2] = B1n.u[0]; BU.u[3] = B1n.u[1];
        dU = __builtin_amdgcn_mfma_f32_16x16x32_f16(aU.h, BU.h, cbm, 0, 0, 0);
        dC = __builtin_amdgcn_mfma_f32_16x16x16f16(aL1a.h, B1n.h, cL1a, 0, 0, 0);
    }

    // body(step m): 12 input exps, grand input rcp, cs updates, 3 Ce exps,
    // grand output rcp, h's, packs, MFMAs in order dA -> dU(spine) -> dC(slack)
    auto body = [&](unsigned xpair, unsigned sel, float wMu, float w4u) {
        float A0 = __builtin_amdgcn_exp2f(dA[0]), F0 = __builtin_amdgcn_exp2f(dA[1]);
        float B0 = __builtin_amdgcn_exp2f(dA[2]), O0 = __builtin_amdgcn_exp2f(dA[3]);
        float A1 = __builtin_amdgcn_exp2f(dU[0]), F1 = __builtin_amdgcn_exp2f(dU[1]);
        float B1 = __builtin_amdgcn_exp2f(dU[2]), O1 = __builtin_amdgcn_exp2f(dU[3]);
        float A2 = __builtin_amdgcn_exp2f(dC[0]), F2 = __builtin_amdgcn_exp2f(dC[1]);
        float B2 = __builtin_amdgcn_exp2f(dC[2]), O2 = __builtin_amdgcn_exp2f(dC[3]);
        float t0 = 1.f + A0, t1 = 1.f + A1, t2 = 1.f + A2;
        float ab0 = fmaf(t0, B0, t0), ab1 = fmaf(t1, B1, t1), ab2 = fmaf(t2, B2, t2);
        float D0 = fmaf(ab0, F0, ab0), D1 = fmaf(ab1, F1, ab1), D2 = fmaf(ab2, F2, ab2);
        float p01 = D0 * D1, p12 = D1 * D2, p02 = D0 * D2;
        float r = __builtin_amdgcn_rcpf(p01 * D2);   // grand input rcp
        float r0 = r * p12, r1 = r * p02, r2 = r * p01;
        float bs0 = fmaf(B0, NTNH, TNHS), bs1 = fmaf(B1, NTNH, TNHS), bs2 = fmaf(B2, NTNH, TNHS);
        float w0 = fmaf(bs0, F0, bs0), w1 = fmaf(bs1, F1, bs1), w2 = fmaf(bs2, F2, bs2);
        cs0 = fmaf(ab0, cs0, w0) * r0;      // TNHS-scaled c; post-rcp = 1 mul
        cs4 = fmaf(ab1, cs4, w1) * r1;
        cs1 = fmaf(ab2, cs1, w2) * r2;
        // output side: 3 Ce exps, grand rcp over (e0*e1*e2)
        float Ce0 = __builtin_amdgcn_exp2f(fminf(cs0, 17.f));
        float Ce1 = __builtin_amdgcn_exp2f(fminf(cs4, 17.f));
        float Ce2 = __builtin_amdgcn_exp2f(fminf(cs1, 17.f));
        float o0 = 1.f + O0, o1 = 1.f + O1, o2 = 1.f + O2;
        float e0 = fmaf(o0, Ce0, o0), e1 = fmaf(o1, Ce1, o1), e2 = fmaf(o2, Ce2, o2);
        float q01 = e0 * e1, q12 = e1 * e2, q02 = e0 * e2;
        float rr = __builtin_amdgcn_rcpf(q01 * e2);  // grand output rcp
        float hA = (1.f - Ce0) * (rr * q12);    // h0u_g (step m)
        float h4 = (1.f - Ce1) * (rr * q02);    // g1: h0u4, g2: h1u4
        unsigned hx0  = pk2(hA, h4);
        HB2 B0n;
        B0n.u[0] = __builtin_amdgcn_perm(xpair, hx0, sel);  B0n.u[1] = 0u;
        dA = __builtin_amdgcn_mfma_f32_16x16x16f16(aL0a.h, B0n.h, cL0a, 0, 0, 0);
        float hC = (1.f - Ce2) * (rr * q01);    // h1u_g (step m-1)
        acc  = fmaf(hC, wMu, acc);              // fused MLP head (t = m-1)
        acc4 = fmaf(h4, w4u, acc4);             // only g2's (h1u4) is used
        unsigned b1lo = pk2(hA, hC);
        unsigned b1hi = hx0 >> 16;
        HB4 BU; BU.u[0] = B0n.u[0]; BU.u[1] = 0u; BU.u[2] = b1lo; BU.u[3] = b1hi;
        dU = __builtin_amdgcn_mfma_f32_16x16x32_f16(aU.h, BU.h, cbm, 0, 0, 0);  // spine
        HB2 B1n; B1n.u[0] = b1lo; B1n.u[1] = b1hi;
        dC = __builtin_amdgcn_mfma_f32_16x16x16f16(aL1a.h, B1n.h, cL1a, 0, 0, 0);
    };

    // prefetch buffers for bodies 1..4: x(2..5) packed, Wc pairs t=0..3
    unsigned xqa, xqb;  float4 wqa, wqb;
    {
        float2 xi0 = *(const float2*)(xp + 2);
        float2 xi1 = *(const float2*)(xp + 4);
        xqa = pk2(xi0.x, xi0.y);  xqb = pk2(xi1.x, xi1.y);
        wqa = *(const float4*)(wsg);
        wqb = *(const float4*)(wsg + 4);
    }
    for (int m = 1; m < 502; m += 4) {          // bodies 1..504, no clamps
        float2 xi0 = *(const float2*)(xp + m + 5);
        float2 xi1 = *(const float2*)(xp + m + 7);
        unsigned nxa = pk2(xi0.x, xi0.y), nxb = pk2(xi1.x, xi1.y);
        float4 nwa = *(const float4*)(wsg + 2 * (m + 3));
        float4 nwb = *(const float4*)(wsg + 2 * (m + 3) + 4);
        body(xqa, selA, wqa.x, wqa.y);
        body(xqa, selB, wqa.z, wqa.w);
        body(xqb, selA, wqb.x, wqb.y);
        body(xqb, selB, wqb.z, wqb.w);
        xqa = nxa; xqb = nxb; wqa = nwa; wqb = nwb;
    }
    {   // block m=505 (bodies 505..508): x prefetch clamped, ws t=508..511
        unsigned nxa = pk2(xp[510], xp[511]);
        unsigned nxb = pk2(xp[511], xp[511]);
        float4 nwa = *(const float4*)(wsg + 2 * 508);
        float4 nwb = *(const float4*)(wsg + 2 * 508 + 4);
        body(xqa, selA, wqa.x, wqa.y);
        body(xqa, selB, wqa.z, wqa.w);
        body(xqb, selA, wqb.x, wqb.y);
        body(xqb, selB, wqb.z, wqb.w);
        xqa = nxa; xqb = nxb; wqa = nwa; wqb = nwb;
    }
    {   // block m=509 (bodies 509..512): no prefetch
        body(xqa, selA, wqa.x, wqa.y);
        body(xqa, selB, wqa.z, wqa.w);
        body(xqb, selA, wqb.x, wqb.y);
        body(xqb, selB, wqb.z, wqb.w);
    }

    // reduce: element e partials live on lanes e, e+16, e+32(+u4), e+48
    float accT = acc + (isg2 ? acc4 : 0.f);
    float t0 = bpermf(e15 << 2, accT);
    float t1 = bpermf((e15 + 16) << 2, accT);
    float t2 = bpermf((e15 + 32) << 2, accT);
    float t3 = bpermf((e15 + 48) << 2, accT);
    if (lane < 16) out[e] = (t0 + t1) + (t2 + t3) + ws[4096];
}

extern "C" void kernel_launch(void* const* d_in, const int* in_sizes, int n_in,
                              void* d_out, int out_size, void* d_ws, size_t ws_size,
                              hipStream_t stream) {
    const float* x    = (const float*)d_in[0];
    const float* Wih0 = (const float*)d_in[1];
    const float* Whh0 = (const float*)d_in[2];
    const float* bih0 = (const float*)d_in[3];
    const float* bhh0 = (const float*)d_in[4];
    const float* Wih1 = (const float*)d_in[5];
    const float* Whh1 = (const float*)d_in[6];
    const float* bih1 = (const float*)d_in[7];
    const float* bhh1 = (const float*)d_in[8];
    const float* W1   = (const float*)d_in[9];
    const float* b1   = (const float*)d_in[10];
    const float* W2   = (const float*)d_in[11];
    const float* b2   = (const float*)d_in[12];
    float* out = (float*)d_out;
    float* ws  = (float*)d_ws;

    collapse_kernel<<<160, 256, 0, stream>>>(W1, b1, W2, b2, ws);
    lstm_fused_kernel<<<BATCH / 16, 64, 0, stream>>>(x, Wih0, Whh0, bih0, bhh0,
                                                     Wih1, Whh1, bih1, bhh1, ws, out);
}